// Round 13
// baseline (60.819 us; speedup 1.0000x reference)
//
#include <hip/hip_runtime.h>
#include <math.h>
#include <stdint.h>

#define RR 1000
#define CC 1024
#define NCLS 81
#define HH 1024.0f
#define MIN_CONF_V 0.05f
#define NMS_THR_V 0.5f
#define NEGV -1e9f

#define KSTRIDE 520   // ushorts per k-step in LDS (512 data + 8 pad -> bank-spread)

typedef __attribute__((ext_vector_type(8))) short bf16x8;
typedef __attribute__((ext_vector_type(16))) float f32x16;

__device__ __forceinline__ unsigned short f2bf(float f) {
    unsigned int u = __float_as_uint(f);
    return (unsigned short)((u + 0x7FFFu + ((u >> 16) & 1u)) >> 16);
}
__device__ __forceinline__ float bf2f(unsigned short h) {
    return __uint_as_float(((unsigned int)h) << 16);
}

// ---------------- Kernel 0: pack w -> 32x32x16 B-fragment order + reset done_ctr ----------------
// B-frag for mfma_f32_32x32x16_bf16: lane l holds B[k][col], col=l&31, k=ks*16+(l>>5)*8+j.
// wh/wl layout: ((ct*64 + ks)*64 + l)*8 + j  (ushort), ct=col-tile 0..2, ks=k-step 0..63
__global__ __launch_bounds__(256) void k0_pack(
    const float* __restrict__ w_cls, const float* __restrict__ w_delta,
    unsigned short* __restrict__ wh, unsigned short* __restrict__ wl,
    int* __restrict__ done_ctr)
{
    if (blockIdx.x == 0 && threadIdx.x == 0) *done_ctr = 0;   // re-init every launch
    const int g = blockIdx.x * 256 + threadIdx.x;    // 0..12287
    const int blk = g >> 6;                          // 0..191 = ct*64 + ks
    const int l = g & 63;
    const int ct = blk >> 6;
    const int ks = blk & 63;
    const int col = ct * 32 + (l & 31);
    const int kbase = ks * 16 + (l >> 5) * 8;
    unsigned short h[8], lo[8];
    #pragma unroll
    for (int j = 0; j < 8; ++j) {
        const int k = kbase + j;
        float v = 0.f;
        if (col < NCLS)          v = w_cls[(size_t)k * NCLS + col];
        else if (col < NCLS + 4) v = w_delta[(size_t)k * 4 + (col - NCLS)];
        h[j] = f2bf(v);
        lo[j] = f2bf(v - bf2f(h[j]));
    }
    const size_t base = ((size_t)blk * 64 + l) * 8;
    uint4 uh, ul;
    uh.x = (unsigned)h[0] | ((unsigned)h[1] << 16);
    uh.y = (unsigned)h[2] | ((unsigned)h[3] << 16);
    uh.z = (unsigned)h[4] | ((unsigned)h[5] << 16);
    uh.w = (unsigned)h[6] | ((unsigned)h[7] << 16);
    ul.x = (unsigned)lo[0] | ((unsigned)lo[1] << 16);
    ul.y = (unsigned)lo[2] | ((unsigned)lo[3] << 16);
    ul.z = (unsigned)lo[4] | ((unsigned)lo[5] << 16);
    ul.w = (unsigned)lo[6] | ((unsigned)lo[7] << 16);
    *(uint4*)&wh[base] = uh;
    *(uint4*)&wl[base] = ul;
}

// ---------------- Kernel 1: GEMM + epilogue + last-block-done NMS ----------------
// 250 blocks x 384 thr (6 waves). Block: 32 rows x 96 cols, K=1024; one staging
// barrier; split-K across waves; LDS-combine; per-row epilogue. Then each block
// fence+atomicAdd(done_ctr); the single block seeing old==249 acquires and runs
// NMS for all 8 batches (output independent of which block wins -> deterministic).
__global__ __launch_bounds__(384) void k1_fused(
    const float* __restrict__ x,
    const unsigned short* __restrict__ wh, const unsigned short* __restrict__ wl,
    const float* __restrict__ b_cls, const float* __restrict__ b_delta,
    const float* __restrict__ rois,
    float* __restrict__ bx_ws, float* __restrict__ sc_ws, float* __restrict__ cid_ws,
    int* __restrict__ done_ctr, float* __restrict__ det)
{
    __shared__ __align__(16) unsigned short XH[64 * KSTRIDE];   // 66560 B
    __shared__ __align__(16) unsigned short XL[64 * KSTRIDE];   // 66560 B
    __shared__ int s_flag;

    const int t = threadIdx.x;
    const int lane = t & 63;
    const int wid = t >> 6;                   // 0..5
    const int ct = wid >> 1;                  // col-tile 0..2
    const int half = wid & 1;                 // K-half
    const int row0 = blockIdx.x * 32;

    // ---- stage whole 32x1024 tile: 8192 float4 slots, 2 batches of 11/thread ----
    #pragma unroll
    for (int batch = 0; batch < 2; ++batch) {
        float4 v[11];
        #pragma unroll
        for (int i = 0; i < 11; ++i) {
            const int s = t + (batch * 11 + i) * 384;
            if (s < 8192)
                v[i] = *(const float4*)(x + (size_t)(row0 + (s >> 8)) * CC + (s & 255) * 4);
        }
        #pragma unroll
        for (int i = 0; i < 11; ++i) {
            const int s = t + (batch * 11 + i) * 384;
            if (s < 8192) {
                const int row = s >> 8;
                const int f4 = s & 255;
                const int ks = f4 >> 2;
                const int q = f4 & 3;
                const int lane_ = ((q >> 1) << 5) + row;
                const int j0 = (q & 1) * 4;
                const size_t us = (size_t)ks * KSTRIDE + lane_ * 8 + j0;
                const unsigned short h0 = f2bf(v[i].x), h1 = f2bf(v[i].y),
                                     h2 = f2bf(v[i].z), h3 = f2bf(v[i].w);
                *(ushort4*)&XH[us] = make_ushort4(h0, h1, h2, h3);
                *(ushort4*)&XL[us] = make_ushort4(
                    f2bf(v[i].x - bf2f(h0)), f2bf(v[i].y - bf2f(h1)),
                    f2bf(v[i].z - bf2f(h2)), f2bf(v[i].w - bf2f(h3)));
            }
        }
    }
    __syncthreads();                          // the ONE staging barrier

    // ---- barrier-free compute: 32 k-steps of K=16, B prefetch depth 4 ----
    const int ks0 = half * 32;
    const unsigned short* whp = wh + (((size_t)ct * 64 + ks0) * 64 + lane) * 8;
    const unsigned short* wlp = wl + (((size_t)ct * 64 + ks0) * 64 + lane) * 8;
    const unsigned short* ap  = &XH[(size_t)ks0 * KSTRIDE + lane * 8];
    const unsigned short* alp = &XL[(size_t)ks0 * KSTRIDE + lane * 8];

    f32x16 acc = {0.f,0.f,0.f,0.f,0.f,0.f,0.f,0.f,0.f,0.f,0.f,0.f,0.f,0.f,0.f,0.f};

    bf16x8 BH[4], BL[4];
    #pragma unroll
    for (int i = 0; i < 4; ++i) {
        BH[i] = *(const bf16x8*)(whp + (size_t)i * 512);
        BL[i] = *(const bf16x8*)(wlp + (size_t)i * 512);
    }

    #pragma unroll
    for (int ks = 0; ks < 32; ++ks) {
        const bf16x8 bh = BH[ks & 3];
        const bf16x8 bl = BL[ks & 3];
        if (ks + 4 < 32) {
            BH[ks & 3] = *(const bf16x8*)(whp + (size_t)(ks + 4) * 512);
            BL[ks & 3] = *(const bf16x8*)(wlp + (size_t)(ks + 4) * 512);
        }
        const bf16x8 ah = *(const bf16x8*)(ap  + (size_t)ks * KSTRIDE);
        const bf16x8 al = *(const bf16x8*)(alp + (size_t)ks * KSTRIDE);
        acc = __builtin_amdgcn_mfma_f32_32x32x16_bf16(ah, bh, acc, 0, 0, 0);
        acc = __builtin_amdgcn_mfma_f32_32x32x16_bf16(ah, bl, acc, 0, 0, 0);
        acc = __builtin_amdgcn_mfma_f32_32x32x16_bf16(al, bh, acc, 0, 0, 0);
    }
    __syncthreads();

    // ---- combine K-halves via LDS aliased over XH ----
    float* outH = (float*)XH;                 // [32][100] half 0
    float* outT = outH + 3200;                // [32][100] half 1
    {
        float* dst = half ? outT : outH;
        const int col = lane & 31;
        #pragma unroll
        for (int reg = 0; reg < 16; ++reg) {
            const int row = (reg & 3) + 8 * (reg >> 2) + 4 * (lane >> 5);
            dst[row * 100 + ct * 32 + col] = acc[reg];
        }
    }
    __syncthreads();

    // ---- fused epilogue: 8 threads per row x 32 rows ----
    if (t < 256) {
        const int row = t >> 3;
        const int e = t & 7;
        float vmax = -INFINITY;
        int imax = 1 << 20;
        float vv[12];
        #pragma unroll
        for (int s = 0; s < 12; ++s) {
            const int cidx = e + 8 * s;
            if (cidx < NCLS) {
                const float val = outH[row * 100 + cidx] + outT[row * 100 + cidx] + b_cls[cidx];
                vv[s] = val;
                if (val > vmax) { vmax = val; imax = cidx; }
            } else vv[s] = -INFINITY;
        }
        #pragma unroll
        for (int mm = 4; mm >= 1; mm >>= 1) {
            const float v2 = __shfl_xor(vmax, mm);
            const int   i2 = __shfl_xor(imax, mm);
            if (v2 > vmax || (v2 == vmax && i2 < imax)) { vmax = v2; imax = i2; }
        }
        float sume = 0.f;
        #pragma unroll
        for (int s = 0; s < 12; ++s) {
            const int cidx = e + 8 * s;
            if (cidx < NCLS) sume += expf(vv[s] - vmax);
        }
        #pragma unroll
        for (int mm = 4; mm >= 1; mm >>= 1) sume += __shfl_xor(sume, mm);

        if (e == 0) {
            const int gr = row0 + row;
            const float score = 1.0f / sume;
            const int cid = imax;
            const float d0 = (outH[row * 100 + 81] + outT[row * 100 + 81] + b_delta[0]) * 0.1f;
            const float d1 = (outH[row * 100 + 82] + outT[row * 100 + 82] + b_delta[1]) * 0.1f;
            const float d2 = (outH[row * 100 + 83] + outT[row * 100 + 83] + b_delta[2]) * 0.2f;
            const float d3 = (outH[row * 100 + 84] + outT[row * 100 + 84] + b_delta[3]) * 0.2f;
            const float y1 = rois[(size_t)gr * 5 + 1] * HH;
            const float x1 = rois[(size_t)gr * 5 + 2] * HH;
            const float y2 = rois[(size_t)gr * 5 + 3] * HH;
            const float x2 = rois[(size_t)gr * 5 + 4] * HH;
            const float h = y2 - y1, w = x2 - x1;
            const float cy = y1 + 0.5f * h + d0 * h;
            const float cx = x1 + 0.5f * w + d1 * w;
            const float h2 = h * expf(d2);
            const float w2 = w * expf(d3);
            const float by1 = fminf(fmaxf(cy - 0.5f * h2, 0.f), HH);
            const float bx1 = fminf(fmaxf(cx - 0.5f * w2, 0.f), HH);
            const float by2 = fminf(fmaxf(cy + 0.5f * h2, 0.f), HH);
            const float bx2 = fminf(fmaxf(cx + 0.5f * w2, 0.f), HH);
            const bool valid = (cid > 0) && (score >= MIN_CONF_V);
            bx_ws[(size_t)gr * 4 + 0] = by1;
            bx_ws[(size_t)gr * 4 + 1] = bx1;
            bx_ws[(size_t)gr * 4 + 2] = by2;
            bx_ws[(size_t)gr * 4 + 3] = bx2;
            sc_ws[gr]  = valid ? score : NEGV;
            cid_ws[gr] = (float)cid;
        }
    }

    // ---- last-block-done handoff (release-acquire via device-scope atomic) ----
    __syncthreads();                          // all epilogue stores issued
    __threadfence();                          // release: make them device-visible
    if (t == 0) {
        const int old = atomicAdd(done_ctr, 1);
        s_flag = (old == (int)gridDim.x - 1) ? 1 : 0;
    }
    __syncthreads();
    if (!s_flag) return;
    __threadfence();                          // acquire: see all blocks' stores

    // ================= Phase C (winner block): NMS for all 8 batches =================
    float* fb = (float*)XH;                   // block-local reuse (our reads are done)
    unsigned long long* keys = (unsigned long long*)fb;   // 256 x 8B
    float* sy1 = fb + 512;
    float* sx1 = fb + 768;
    float* sy2 = fb + 1024;
    float* sx2 = fb + 1280;
    float* scl = fb + 1536;
    float* ssc = fb + 1792;
    unsigned char* supp = (unsigned char*)(fb + 2048);    // 256 B
    int* s_cnt = (int*)(fb + 2112);
    int* s_num = (int*)(fb + 2113);

    for (int b = 0; b < 8; ++b) {
        const int base = b * RR;

        if (t < 256) keys[t] = 0ull;
        if (t == 0) { *s_cnt = 0; *s_num = 0; }
        __syncthreads();

        for (int rr = t; rr < RR; rr += 384) {
            const float s = sc_ws[base + rr];
            if (s > NEGV * 0.5f) {
                const int i = atomicAdd(s_num, 1);
                if (i < 256) {
                    unsigned int u = __float_as_uint(s) | 0x80000000u;
                    keys[i] = ((unsigned long long)u << 32) | (unsigned int)(~(unsigned int)rr);
                }
            }
        }
        __syncthreads();
        const int V = (*s_num < 256) ? *s_num : 256;

        if (V > 1) {                          // skip sort when 0/1 valid (exact)
            for (int k = 2; k <= 256; k <<= 1) {
                for (int j = k >> 1; j > 0; j >>= 1) {
                    if (t < 256) {
                        const int ixj = t ^ j;
                        if (ixj > t) {
                            const unsigned long long a = keys[t];
                            const unsigned long long c = keys[ixj];
                            const bool desc = ((t & k) == 0);
                            if (desc ? (a < c) : (a > c)) { keys[t] = c; keys[ixj] = a; }
                        }
                    }
                    __syncthreads();
                }
            }
        }

        if (t < 256) {
            if (t < V) {
                const int orig = (int)(~(unsigned int)keys[t]);
                const int g = base + orig;
                sy1[t] = bx_ws[(size_t)g * 4 + 0];
                sx1[t] = bx_ws[(size_t)g * 4 + 1];
                sy2[t] = bx_ws[(size_t)g * 4 + 2];
                sx2[t] = bx_ws[(size_t)g * 4 + 3];
                scl[t] = cid_ws[g];
                ssc[t] = sc_ws[g];
            } else {
                sy1[t] = sx1[t] = sy2[t] = sx2[t] = 0.f;
                scl[t] = -1.f;
                ssc[t] = NEGV;
            }
            supp[t] = 0;
        }
        __syncthreads();

        for (int i = 0; i < V; ++i) {
            __syncthreads();
            if (*s_cnt >= 100) break;
            if (!supp[i]) {
                if (t > i && t < V && scl[t] == scl[i]) {
                    const float yy1 = fmaxf(sy1[i], sy1[t]);
                    const float xx1 = fmaxf(sx1[i], sx1[t]);
                    const float yy2 = fminf(sy2[i], sy2[t]);
                    const float xx2 = fminf(sx2[i], sx2[t]);
                    const float inter = fmaxf(yy2 - yy1, 0.f) * fmaxf(xx2 - xx1, 0.f);
                    const float ai = (sy2[i] - sy1[i]) * (sx2[i] - sx1[i]);
                    const float at = (sy2[t] - sy1[t]) * (sx2[t] - sx1[t]);
                    const float uni = ai + at - inter;
                    if (inter / fmaxf(uni, 1e-8f) > NMS_THR_V) supp[t] = 1;
                }
                if (t == 0) {
                    const int slot = *s_cnt;
                    if (slot < 100) {
                        float* o = det + ((size_t)b * 100 + slot) * 6;
                        o[0] = sy1[i]; o[1] = sx1[i]; o[2] = sy2[i]; o[3] = sx2[i];
                        o[4] = scl[i]; o[5] = ssc[i];
                    }
                    *s_cnt = slot + 1;
                }
            }
        }
        __syncthreads();
        int cnt = *s_cnt;
        if (cnt > 100) cnt = 100;
        for (int idx = t; idx < 600; idx += 384) {
            if (idx >= cnt * 6) det[(size_t)b * 600 + idx] = 0.f;
        }
        __syncthreads();
    }
}

extern "C" void kernel_launch(void* const* d_in, const int* in_sizes, int n_in,
                              void* d_out, int out_size, void* d_ws, size_t ws_size,
                              hipStream_t stream) {
    const float* x       = (const float*)d_in[0];
    const float* w_cls   = (const float*)d_in[1];
    const float* b_cls   = (const float*)d_in[2];
    const float* w_delta = (const float*)d_in[3];
    const float* b_delta = (const float*)d_in[4];
    const float* rois    = (const float*)d_in[5];
    float* det = (float*)d_out;

    float* bx_ws   = (float*)d_ws;               // [8000][4]
    float* sc_ws   = bx_ws + 8000 * 4;           // [8000]
    float* cid_ws  = sc_ws + 8000;               // [8000]
    unsigned short* wh = (unsigned short*)(cid_ws + 8000);   // 98304 ushort
    unsigned short* wl = wh + 98304;             // 98304 ushort
    int* done_ctr  = (int*)(wl + 98304);         // 1 int, zeroed by k0 each launch

    k0_pack<<<48, 256, 0, stream>>>(w_cls, w_delta, wh, wl, done_ctr);
    k1_fused<<<250, 384, 0, stream>>>(x, wh, wl, b_cls, b_delta, rois,
                                      bx_ws, sc_ws, cid_ws, done_ctr, det);
}

// Round 14
// 30.436 us; speedup vs baseline: 1.9982x; 1.9982x over previous
//
#include <hip/hip_runtime.h>
#include <math.h>
#include <stdint.h>

#define RR 1000
#define CC 1024
#define NCLS 81
#define HH 1024.0f
#define MIN_CONF_V 0.05f
#define NMS_THR_V 0.5f
#define NEGV -1e9f

#define KS2 520   // ushorts per 32-k step in LDS (512 data + 8 pad)

typedef __attribute__((ext_vector_type(8))) short bf16x8;
typedef __attribute__((ext_vector_type(4))) float f32x4;

__device__ __forceinline__ unsigned short f2bf(float f) {
    unsigned int u = __float_as_uint(f);
    return (unsigned short)((u + 0x7FFFu + ((u >> 16) & 1u)) >> 16);
}
__device__ __forceinline__ float bf2f(unsigned short h) {
    return __uint_as_float(((unsigned int)h) << 16);
}

// ---------------- Kernel 0: pack w -> 16x16x32 B-fragment order, bf16 hi/lo ----------------
// B-frag (mfma_f32_16x16x32_bf16): lane l holds B[k][col], col=ct*16+(l&15),
// k = sg*32 + (l>>4)*8 + j.  wh/wl[((ct*32+sg)*64 + l)*8 + j], ct 0..5, sg 0..31.
__global__ __launch_bounds__(256) void k0_pack(
    const float* __restrict__ w_cls, const float* __restrict__ w_delta,
    unsigned short* __restrict__ wh, unsigned short* __restrict__ wl)
{
    const int g = blockIdx.x * 256 + threadIdx.x;    // 0..12287
    const int unit = g >> 6;                         // 0..191 = ct*32 + sg
    const int l = g & 63;
    const int ct = unit >> 5;
    const int sg = unit & 31;
    const int col = ct * 16 + (l & 15);
    const int kbase = sg * 32 + (l >> 4) * 8;
    unsigned short h[8], lo[8];
    #pragma unroll
    for (int j = 0; j < 8; ++j) {
        const int k = kbase + j;
        float v = 0.f;
        if (col < NCLS)          v = w_cls[(size_t)k * NCLS + col];
        else if (col < NCLS + 4) v = w_delta[(size_t)k * 4 + (col - NCLS)];
        h[j] = f2bf(v);
        lo[j] = f2bf(v - bf2f(h[j]));
    }
    const size_t base = ((size_t)unit * 64 + l) * 8;
    uint4 uh, ul;
    uh.x = (unsigned)h[0] | ((unsigned)h[1] << 16);
    uh.y = (unsigned)h[2] | ((unsigned)h[3] << 16);
    uh.z = (unsigned)h[4] | ((unsigned)h[5] << 16);
    uh.w = (unsigned)h[6] | ((unsigned)h[7] << 16);
    ul.x = (unsigned)lo[0] | ((unsigned)lo[1] << 16);
    ul.y = (unsigned)lo[2] | ((unsigned)lo[3] << 16);
    ul.z = (unsigned)lo[4] | ((unsigned)lo[5] << 16);
    ul.w = (unsigned)lo[6] | ((unsigned)lo[7] << 16);
    *(uint4*)&wh[base] = uh;
    *(uint4*)&wl[base] = ul;
}

// ---------------- Kernel 1: BM=16 MFMA GEMM (split-bf16 x3) + fused epilogue ----------------
// 500 blocks x 384 thr (6 waves); 2 blocks/CU (67 KB LDS), 12 waves/CU for the
// cold HBM stream. Wave = col-tile ct (16 cols), full K=1024 per wave, one
// staging barrier, B prefetch depth 4 from L2/L3.
__global__ __launch_bounds__(384, 3) void k1_head(
    const float* __restrict__ x,
    const unsigned short* __restrict__ wh, const unsigned short* __restrict__ wl,
    const float* __restrict__ b_cls, const float* __restrict__ b_delta,
    const float* __restrict__ rois,
    float* __restrict__ bx_ws, float* __restrict__ sc_ws, float* __restrict__ cid_ws)
{
    // A-frag layout: XH[sg*KS2 + lane*8 + j] = bf16(x[row0+(lane&15)][sg*32+(lane>>4)*8+j])
    __shared__ __align__(16) unsigned short XH[32 * KS2];   // 33280 B
    __shared__ __align__(16) unsigned short XL[32 * KS2];   // 33280 B

    const int t = threadIdx.x;
    const int lane = t & 63;
    const int ct = t >> 6;                    // wave = col-tile 0..5
    const int row0 = blockIdx.x * 16;

    // ---- issue all staging loads first: 4096 float4 slots, 11 per thread ----
    float4 v[11];
    #pragma unroll
    for (int i = 0; i < 11; ++i) {
        const int s = t + i * 384;
        if (i < 10 || s < 4096)
            v[i] = *(const float4*)(x + (size_t)(row0 + (s >> 8)) * CC + (s & 255) * 4);
    }

    // ---- B-frag pointers + depth-4 preload (L2/L3; overlaps staging) ----
    const unsigned short* whp = wh + (((size_t)ct * 32) * 64 + lane) * 8;
    const unsigned short* wlp = wl + (((size_t)ct * 32) * 64 + lane) * 8;
    bf16x8 BH[4], BL[4];
    #pragma unroll
    for (int i = 0; i < 4; ++i) {
        BH[i] = *(const bf16x8*)(whp + (size_t)i * 512);
        BL[i] = *(const bf16x8*)(wlp + (size_t)i * 512);
    }

    // ---- convert + write to LDS in A-frag layout ----
    #pragma unroll
    for (int i = 0; i < 11; ++i) {
        const int s = t + i * 384;
        if (i < 10 || s < 4096) {
            const int row = s >> 8;               // 0..15
            const int f4 = s & 255;               // k-quad 0..255
            const int sg = f4 >> 3;               // 0..31
            const int j0 = (f4 & 1) * 4;
            const int lane_ = ((f4 >> 1) & 3) * 16 + row;
            const size_t us = (size_t)sg * KS2 + lane_ * 8 + j0;
            const unsigned short h0 = f2bf(v[i].x), h1 = f2bf(v[i].y),
                                 h2 = f2bf(v[i].z), h3 = f2bf(v[i].w);
            *(ushort4*)&XH[us] = make_ushort4(h0, h1, h2, h3);
            *(ushort4*)&XL[us] = make_ushort4(
                f2bf(v[i].x - bf2f(h0)), f2bf(v[i].y - bf2f(h1)),
                f2bf(v[i].z - bf2f(h2)), f2bf(v[i].w - bf2f(h3)));
        }
    }
    __syncthreads();                          // the ONE staging barrier

    // ---- barrier-free compute: 32 steps of K=32, 3 MFMA each ----
    const unsigned short* ap  = &XH[lane * 8];
    const unsigned short* alp = &XL[lane * 8];
    f32x4 acc = {0.f, 0.f, 0.f, 0.f};

    #pragma unroll
    for (int sg = 0; sg < 32; ++sg) {
        const bf16x8 bh = BH[sg & 3];
        const bf16x8 bl = BL[sg & 3];
        if (sg + 4 < 32) {                    // refill slot (static index via unroll)
            BH[sg & 3] = *(const bf16x8*)(whp + (size_t)(sg + 4) * 512);
            BL[sg & 3] = *(const bf16x8*)(wlp + (size_t)(sg + 4) * 512);
        }
        const bf16x8 ah = *(const bf16x8*)(ap  + (size_t)sg * KS2);
        const bf16x8 al = *(const bf16x8*)(alp + (size_t)sg * KS2);
        acc = __builtin_amdgcn_mfma_f32_16x16x32_bf16(ah, bh, acc, 0, 0, 0);
        acc = __builtin_amdgcn_mfma_f32_16x16x32_bf16(ah, bl, acc, 0, 0, 0);
        acc = __builtin_amdgcn_mfma_f32_16x16x32_bf16(al, bh, acc, 0, 0, 0);
    }
    __syncthreads();                          // all XH/XL reads done

    // ---- C write: col = lane&15, row = (lane>>4)*4 + r  (r5-verified) ----
    float* outb = (float*)XH;                 // alias: [16][104]
    #pragma unroll
    for (int r = 0; r < 4; ++r)
        outb[((lane >> 4) * 4 + r) * 104 + ct * 16 + (lane & 15)] = acc[r];
    __syncthreads();

    // ---- fused epilogue: 16 threads per row x 16 rows (r5-verified) ----
    if (t < 256) {
        const int row = t >> 4;
        const int e = t & 15;
        float vmax = -INFINITY;
        int imax = 1 << 20;
        float vv[6];
        #pragma unroll
        for (int s = 0; s < 6; ++s) {
            const int cidx = e + 16 * s;
            if (cidx < NCLS) {
                const float val = outb[row * 104 + cidx] + b_cls[cidx];
                vv[s] = val;
                if (val > vmax) { vmax = val; imax = cidx; }
            } else vv[s] = -INFINITY;
        }
        #pragma unroll
        for (int m = 8; m >= 1; m >>= 1) {
            const float v2 = __shfl_xor(vmax, m);
            const int   i2 = __shfl_xor(imax, m);
            if (v2 > vmax || (v2 == vmax && i2 < imax)) { vmax = v2; imax = i2; }
        }
        float sume = 0.f;
        #pragma unroll
        for (int s = 0; s < 6; ++s) {
            const int cidx = e + 16 * s;
            if (cidx < NCLS) sume += expf(vv[s] - vmax);
        }
        #pragma unroll
        for (int m = 8; m >= 1; m >>= 1) sume += __shfl_xor(sume, m);

        if (e == 0) {
            const int gr = row0 + row;
            const float score = 1.0f / sume;
            const int cid = imax;
            const float d0 = (outb[row * 104 + 81] + b_delta[0]) * 0.1f;
            const float d1 = (outb[row * 104 + 82] + b_delta[1]) * 0.1f;
            const float d2 = (outb[row * 104 + 83] + b_delta[2]) * 0.2f;
            const float d3 = (outb[row * 104 + 84] + b_delta[3]) * 0.2f;
            const float y1 = rois[(size_t)gr * 5 + 1] * HH;
            const float x1 = rois[(size_t)gr * 5 + 2] * HH;
            const float y2 = rois[(size_t)gr * 5 + 3] * HH;
            const float x2 = rois[(size_t)gr * 5 + 4] * HH;
            const float h = y2 - y1, w = x2 - x1;
            const float cy = y1 + 0.5f * h + d0 * h;
            const float cx = x1 + 0.5f * w + d1 * w;
            const float h2 = h * expf(d2);
            const float w2 = w * expf(d3);
            const float by1 = fminf(fmaxf(cy - 0.5f * h2, 0.f), HH);
            const float bx1 = fminf(fmaxf(cx - 0.5f * w2, 0.f), HH);
            const float by2 = fminf(fmaxf(cy + 0.5f * h2, 0.f), HH);
            const float bx2 = fminf(fmaxf(cx + 0.5f * w2, 0.f), HH);
            const bool valid = (cid > 0) && (score >= MIN_CONF_V);
            bx_ws[(size_t)gr * 4 + 0] = by1;
            bx_ws[(size_t)gr * 4 + 1] = bx1;
            bx_ws[(size_t)gr * 4 + 2] = by2;
            bx_ws[(size_t)gr * 4 + 3] = bx2;
            sc_ws[gr]  = valid ? score : NEGV;
            cid_ws[gr] = (float)cid;
        }
    }
}

// ---------------- Kernel 2: compact valid -> sort (skip if V<=1) -> NMS -> emit ----------------
__global__ __launch_bounds__(256) void k2_nms(
    const float* __restrict__ bx_ws, const float* __restrict__ sc_ws,
    const float* __restrict__ cid_ws, float* __restrict__ det)
{
    __shared__ unsigned long long keys[256];
    __shared__ float sy1[256], sx1[256], sy2[256], sx2[256];
    __shared__ float scl[256], ssc[256];
    __shared__ unsigned char supp[256];
    __shared__ int s_cnt, s_num;

    const int b = blockIdx.x;
    const int t = threadIdx.x;
    const int base = b * RR;

    keys[t] = 0ull;
    if (t == 0) { s_cnt = 0; s_num = 0; }
    __syncthreads();

    for (int rr = t; rr < RR; rr += 256) {
        const float s = sc_ws[base + rr];
        if (s > NEGV * 0.5f) {
            const int i = atomicAdd(&s_num, 1);
            if (i < 256) {
                unsigned int u = __float_as_uint(s) | 0x80000000u;
                keys[i] = ((unsigned long long)u << 32) | (unsigned int)(~(unsigned int)rr);
            }
        }
    }
    __syncthreads();
    const int V = (s_num < 256) ? s_num : 256;

    if (V > 1) {
        for (int k = 2; k <= 256; k <<= 1) {
            for (int j = k >> 1; j > 0; j >>= 1) {
                const int ixj = t ^ j;
                if (ixj > t) {
                    const unsigned long long a = keys[t];
                    const unsigned long long c = keys[ixj];
                    const bool desc = ((t & k) == 0);
                    if (desc ? (a < c) : (a > c)) { keys[t] = c; keys[ixj] = a; }
                }
                __syncthreads();
            }
        }
    }

    if (t < V) {
        const int orig = (int)(~(unsigned int)keys[t]);
        const int g = base + orig;
        sy1[t] = bx_ws[(size_t)g * 4 + 0];
        sx1[t] = bx_ws[(size_t)g * 4 + 1];
        sy2[t] = bx_ws[(size_t)g * 4 + 2];
        sx2[t] = bx_ws[(size_t)g * 4 + 3];
        scl[t] = cid_ws[g];
        ssc[t] = sc_ws[g];
    } else {
        sy1[t] = sx1[t] = sy2[t] = sx2[t] = 0.f;
        scl[t] = -1.f;
        ssc[t] = NEGV;
    }
    supp[t] = 0;
    __syncthreads();

    for (int i = 0; i < V; ++i) {
        __syncthreads();
        if (s_cnt >= 100) break;
        if (!supp[i]) {
            if (t > i && t < V && scl[t] == scl[i]) {
                const float yy1 = fmaxf(sy1[i], sy1[t]);
                const float xx1 = fmaxf(sx1[i], sx1[t]);
                const float yy2 = fminf(sy2[i], sy2[t]);
                const float xx2 = fminf(sx2[i], sx2[t]);
                const float inter = fmaxf(yy2 - yy1, 0.f) * fmaxf(xx2 - xx1, 0.f);
                const float ai = (sy2[i] - sy1[i]) * (sx2[i] - sx1[i]);
                const float at = (sy2[t] - sy1[t]) * (sx2[t] - sx1[t]);
                const float uni = ai + at - inter;
                if (inter / fmaxf(uni, 1e-8f) > NMS_THR_V) supp[t] = 1;
            }
            if (t == 0) {
                const int slot = s_cnt;
                if (slot < 100) {
                    float* o = det + ((size_t)b * 100 + slot) * 6;
                    o[0] = sy1[i]; o[1] = sx1[i]; o[2] = sy2[i]; o[3] = sx2[i];
                    o[4] = scl[i]; o[5] = ssc[i];
                }
                s_cnt = slot + 1;
            }
        }
    }
    __syncthreads();
    int cnt = s_cnt;
    if (cnt > 100) cnt = 100;
    for (int idx = t; idx < 600; idx += 256) {
        if (idx >= cnt * 6) det[(size_t)b * 600 + idx] = 0.f;
    }
}

extern "C" void kernel_launch(void* const* d_in, const int* in_sizes, int n_in,
                              void* d_out, int out_size, void* d_ws, size_t ws_size,
                              hipStream_t stream) {
    const float* x       = (const float*)d_in[0];
    const float* w_cls   = (const float*)d_in[1];
    const float* b_cls   = (const float*)d_in[2];
    const float* w_delta = (const float*)d_in[3];
    const float* b_delta = (const float*)d_in[4];
    const float* rois    = (const float*)d_in[5];
    float* out = (float*)d_out;

    float* bx_ws   = (float*)d_ws;               // [8000][4]
    float* sc_ws   = bx_ws + 8000 * 4;           // [8000]
    float* cid_ws  = sc_ws + 8000;               // [8000]
    unsigned short* wh = (unsigned short*)(cid_ws + 8000);   // 6*32*64*8 = 98304 ushort
    unsigned short* wl = wh + 98304;

    k0_pack<<<48, 256, 0, stream>>>(w_cls, w_delta, wh, wl);
    k1_head<<<500, 384, 0, stream>>>(x, wh, wl, b_cls, b_delta, rois,
                                     bx_ws, sc_ws, cid_ws);
    k2_nms<<<8, 256, 0, stream>>>(bx_ws, sc_ws, cid_ws, out);
}